// Round 9
// baseline (705.073 us; speedup 1.0000x reference)
//
#include <hip/hip_runtime.h>
#include <hip/hip_bf16.h>
#include <stdint.h>

typedef __bf16 bf16x8 __attribute__((ext_vector_type(8)));
typedef float f32x4 __attribute__((ext_vector_type(4)));
typedef unsigned short ushort8v __attribute__((ext_vector_type(8)));

// Problem constants
#define NB    16
#define CIN   256
#define COUT  256
#define HH    128
#define WW    128

// ws layout (bytes)
#define OFF_ZROW  0u                    // 65536 zeroed page (one fake xT row)
#define OFF_COFF  (1u << 16)            // 2*16*256 f32 = 8 KB
#define OFF_TMPS  (1u << 17)            // 16*16*768 f32 = 768 KB
#define OFF_WEFF  (1u << 20)            // 16*9*256*256 bf16 = 18 MB
#define OFF_XT    (20u * 1024u * 1024u) // G * 8 MB bf16 channels-last x
#define XT_PER_B  (128u * 128u * 256u * 2u)

__device__ inline void gload16(const void* g, void* l) {
  __builtin_amdgcn_global_load_lds(
      (const __attribute__((address_space(1))) void*)g,
      (__attribute__((address_space(3))) void*)l, 16, 0, 0);
}

__device__ inline ushort f2bf(float f) {
  __hip_bfloat16 h = __float2bfloat16(f);
  union { __hip_bfloat16 b; ushort u; } cv;
  cv.b = h;
  return cv.u;
}

// ---------------- kernel 1: embed MLP -> coff[2][16][16][16] ----------------
__global__ void k_coff(const float* __restrict__ wms,
                       const float* __restrict__ w1a, const float* __restrict__ b1a,
                       const float* __restrict__ w2a, const float* __restrict__ b2a,
                       const float* __restrict__ w1b, const float* __restrict__ b1b,
                       const float* __restrict__ w2b, const float* __restrict__ b2b,
                       float* __restrict__ coff) {
  int br = blockIdx.x >> 4, b = blockIdx.x & 15;
  const float* w1 = br ? w1b : w1a;
  const float* b1 = br ? b1b : b1a;
  const float* w2 = br ? w2b : w2a;
  const float* b2 = br ? b2b : b2a;
  const float* v = wms + (br * 16 + b) * 32;
  __shared__ float h[128];
  int t = threadIdx.x;
  if (t < 128) {
    float a = b1[t];
#pragma unroll
    for (int i = 0; i < 32; ++i) a += w1[t * 32 + i] * v[i];
    h[t] = a >= 0.f ? a : 0.2f * a;
  }
  __syncthreads();
  float a = b2[t];
  for (int j = 0; j < 128; ++j) a += w2[t * 128 + j] * h[j];
  coff[(br * 16 + b) * 256 + t] = a;
}

// ------------- kernel 2a: tmpS[b][r][c] = coff1@A1 + coff2@A2 ---------------
__global__ void k_tmps(const float* __restrict__ coff,
                       const float* __restrict__ A1, const float* __restrict__ A2,
                       float* __restrict__ tmpS) {
  int b = blockIdx.x >> 4, r = blockIdx.x & 15;
  __shared__ float c1[16], c2[16];
  int t = threadIdx.x;
  if (t < 16) {
    c1[t] = coff[b * 256 + r * 16 + t];
    c2[t] = coff[(16 + b) * 256 + r * 16 + t];
  }
  __syncthreads();
  for (int c = t; c < 768; c += 256) {
    float s = 0.f;
#pragma unroll
    for (int q = 0; q < 16; ++q) s += c1[q] * A1[q * 768 + c] + c2[q] * A2[q * 768 + c];
    tmpS[(b * 16 + r) * 768 + c] = s;
  }
}

// ------- kernel 2b: Weff[b][tt][co][ci] = conv_w + loraB @ tmpS (bf16) -------
__global__ __launch_bounds__(256) void k_weff(const float* __restrict__ conv_w,
                                              const float* __restrict__ loraB,
                                              const float* __restrict__ tmpS,
                                              __hip_bfloat16* __restrict__ Weff) {
  int bid = blockIdx.x;
  int co = bid & 255, b = bid >> 8;
  int t = threadIdx.x;
  __shared__ float Bs[3][16];
  __shared__ ushort obuf[2304];
  if (t < 48) Bs[t >> 4][t & 15] = loraB[(co * 3 + (t >> 4)) * 16 + (t & 15)];
  __syncthreads();
  const float* T = tmpS + (size_t)b * 16 * 768;
  const float* W = conv_w + (size_t)co * 2304;
#pragma unroll
  for (int k = 0; k < 3; ++k) {
#pragma unroll
    for (int cc = 0; cc < 3; ++cc) {
      int c = cc * 256 + t;
      float s = W[k * 768 + c];
#pragma unroll
      for (int r = 0; r < 16; ++r) s += Bs[k][r] * T[r * 768 + c];
      int f = k * 768 + c;  // local flat over (ci,kh,kw) for this co
      int ci = f / 9, tt = f - ci * 9;
      obuf[tt * 256 + ci] = f2bf(s);
    }
  }
  __syncthreads();
#pragma unroll
  for (int tt = 0; tt < 9; ++tt)
    ((ushort*)Weff)[((size_t)(b * 9 + tt) * 256 + co) * 256 + t] = obuf[tt * 256 + t];
}

// -------- kernel 3: x (f32, NCHW) -> xT (bf16, N H W C channels-last) --------
__global__ __launch_bounds__(256) void k_xt(const float* __restrict__ x,
                                            __hip_bfloat16* __restrict__ xT, int b0) {
  __shared__ ushort t[32][132];
  int bid = blockIdx.x;
  int cb = bid & 7, h = (bid >> 3) & 127, bp = bid >> 10;
  int b = b0 + bp;
  int tid = threadIdx.x;
  int ci2 = tid >> 5, w4 = (tid & 31) * 4;
  const float* srcb = x + ((size_t)(b * 256 + cb * 32) * 128 + h) * 128;
#pragma unroll
  for (int k = 0; k < 4; ++k) {
    int c = ci2 + k * 8;
    float4 v = *(const float4*)(srcb + (size_t)c * 16384 + w4);
    ushort4 u;
    u.x = f2bf(v.x);
    u.y = f2bf(v.y);
    u.z = f2bf(v.z);
    u.w = f2bf(v.w);
    *(ushort4*)&t[c][w4] = u;
  }
  __syncthreads();
  int w = tid >> 1, hf = tid & 1;
  ushort8v o0, o1;
#pragma unroll
  for (int j = 0; j < 8; ++j) {
    o0[j] = t[hf * 16 + j][w];
    o1[j] = t[hf * 16 + 8 + j][w];
  }
  ushort* dst = (ushort*)xT + (size_t)bp * 128 * 128 * 256 +
                ((size_t)h * 128 + w) * 256 + cb * 32 + hf * 16;
  *(ushort8v*)dst = o0;
  *(ushort8v*)(dst + 8) = o1;
}

// ------------------- kernel 4: per-sample implicit-GEMM conv ------------------
// AITER-style: W (A-frags) streamed straight from L2-resident global memory
// into registers, software-pipelined one tap ahead (aA/aB alternation, all
// compile-time indexed). Only x lives in LDS (25 KB, proven 0-conflict
// swizzle). 2 raw barriers + 1 counted vmcnt(8) per ci-chunk (16 barriers
// total vs 96). 2 blocks/CU (VGPR-capped via __launch_bounds__(256,2)).
__global__ __launch_bounds__(256, 2) void k_conv(
    const __hip_bfloat16* __restrict__ xT,
    const __hip_bfloat16* __restrict__ Weff,
    const __hip_bfloat16* __restrict__ zrow,
    const float* __restrict__ cbias,
    float* __restrict__ out, int b0) {
  // xs[ri][wi][ci] : ri 0..2 -> x row h0-1+ri ; wi 0..129 -> w = wi-1 ; 32 ci
  __shared__ __align__(16) __hip_bfloat16 xs[3 * 130 * 32];   // 24,960 B

  // XCD-aware swizzle (nwg = G*128, always % 8 == 0); consecutive swizzled
  // bids on one XCD share the same sample b -> Weff[b] (1.125 MB) L2-resident.
  int nwg = gridDim.x;
  int bid0 = blockIdx.x;
  int bid = (bid0 & 7) * (nwg >> 3) + (bid0 >> 3);

  int h0 = bid & 127, bp = bid >> 7;
  int b = b0 + bp;

  int tid = threadIdx.x;
  int wid = tid >> 6, lane = tid & 63;
  int l15 = lane & 15, lh = lane >> 4;
  int wm = wid >> 1;                // co half (0/1)
  int w0 = (wid & 1) * 64;          // w half
  int lrow = lane >> 2;
  int sgx = (lane & 3) ^ (((1 + lrow) >> 1) & 3);  // x-stage source granule

  // zero the w-pad columns (wi = 0 and wi = 129); never overwritten after
  if (tid < 192) {
    int ri = tid >> 6, which = (tid >> 5) & 1, ci = tid & 31;
    ((ushort*)xs)[ri * 4160 + (which ? 129 : 0) * 32 + ci] = 0;
  }

  // ---- precomputed offsets (elements) ----
  int a_off = (wm * 128 + l15) * 256 + lh * 8;   // A-frag lane offset in Weff slab
  int b_base0 = (w0 + l15 + 0) * 32 + ((lh ^ (((l15 + 0) >> 1) & 3)) * 8);
  int b_base1 = (w0 + l15 + 1) * 32 + ((lh ^ (((l15 + 1) >> 1) & 3)) * 8);
  int b_base2 = (w0 + l15 + 2) * 32 + ((lh ^ (((l15 + 2) >> 1) & 3)) * 8);
  int xoff = lrow * 256 + sgx * 8;               // + wblk*4096 + c0

  const __hip_bfloat16* xTb = xT + (size_t)bp * 128 * 128 * 256;
  const __hip_bfloat16* r0 = (h0 > 0)   ? xTb + (size_t)(h0 - 1) * 32768 : zrow;
  const __hip_bfloat16* r1 = xTb + (size_t)h0 * 32768;
  const __hip_bfloat16* r2 = (h0 < 127) ? xTb + (size_t)(h0 + 1) * 32768 : zrow;
  const __hip_bfloat16* wbase = Weff + ((size_t)(b * 9) << 16);  // [tt][co][ci]

  f32x4 acc[8][4];
#pragma unroll
  for (int mf = 0; mf < 8; ++mf)
#pragma unroll
    for (int nf = 0; nf < 4; ++nf) acc[mf][nf] = (f32x4){0.f, 0.f, 0.f, 0.f};

  __syncthreads();  // pads visible

  bf16x8 aA[8], aB[8];

// one tap: MFMA with CUR; if PREF, issue next tap's A loads into NXT first.
#define CONV_TAP(CUR, NXT, TT, KH, KW, PREF)                                   \
  {                                                                            \
    if (PREF) {                                                                \
      const __hip_bfloat16* an = wb + (((TT) + 1) << 16);                      \
      _Pragma("unroll")                                                        \
      for (int mf = 0; mf < 8; ++mf)                                           \
        NXT[mf] = *(const bf16x8*)(an + mf * 4096);                            \
    }                                                                          \
    const int bb = (KW == 0) ? b_base0 : ((KW == 1) ? b_base1 : b_base2);      \
    bf16x8 bfr[4];                                                             \
    _Pragma("unroll")                                                          \
    for (int nf = 0; nf < 4; ++nf)                                             \
      bfr[nf] = *(const bf16x8*)&xs[(KH) * 4160 + bb + nf * 512];              \
    __builtin_amdgcn_s_setprio(1);                                             \
    _Pragma("unroll")                                                          \
    for (int mf = 0; mf < 8; ++mf)                                             \
      _Pragma("unroll")                                                        \
      for (int nf = 0; nf < 4; ++nf)                                           \
        acc[mf][nf] = __builtin_amdgcn_mfma_f32_16x16x32_bf16(                 \
            CUR[mf], bfr[nf], acc[mf][nf], 0, 0, 0);                           \
    __builtin_amdgcn_s_setprio(0);                                             \
  }

#pragma unroll 1
  for (int cb8 = 0; cb8 < 8; ++cb8) {
    int c0 = cb8 * 32;
    __builtin_amdgcn_s_barrier();  // all waves done reading xs (lgkm drained
                                   // per-wave before their MFMAs)

    // stage x: 24 x (1KB gload16); slot = k*4+wid -> ri = k>>1 compile-time
#pragma unroll
    for (int k = 0; k < 6; ++k) {
      const int ri = k >> 1;
      int wblk = (k & 1) * 4 + wid;
      const __hip_bfloat16* rp = (ri == 0) ? r0 : ((ri == 1) ? r1 : r2);
      gload16((const void*)(rp + wblk * 4096 + c0 + xoff),
              (void*)(xs + ri * 4160 + (1 + wblk * 16) * 32));
    }

    // prefetch A for tap 0 of this chunk (stays in flight across the wait)
    const __hip_bfloat16* wb = wbase + c0 + a_off;
#pragma unroll
    for (int mf = 0; mf < 8; ++mf) aA[mf] = *(const bf16x8*)(wb + mf * 4096);

    // x-stage (6 oldest) drained; 8 A loads may remain in flight
    asm volatile("s_waitcnt vmcnt(8)" ::: "memory");
    __builtin_amdgcn_s_barrier();

    CONV_TAP(aA, aB, 0, 0, 0, 1);
    CONV_TAP(aB, aA, 1, 0, 1, 1);
    CONV_TAP(aA, aB, 2, 0, 2, 1);
    CONV_TAP(aB, aA, 3, 1, 0, 1);
    CONV_TAP(aA, aB, 4, 1, 1, 1);
    CONV_TAP(aB, aA, 5, 1, 2, 1);
    CONV_TAP(aA, aB, 6, 2, 0, 1);
    CONV_TAP(aB, aA, 7, 2, 1, 1);
    CONV_TAP(aA, aB, 8, 2, 2, 0);
  }
#undef CONV_TAP

  // epilogue: D[m][n]: m(co) = (lane>>4)*4 + r, n(px) = lane&15
#pragma unroll
  for (int mf = 0; mf < 8; ++mf) {
    int cobase = wm * 128 + mf * 16 + lh * 4;
#pragma unroll
    for (int r = 0; r < 4; ++r) {
      int co = cobase + r;
      float bias = cbias[co];
      size_t obase = ((size_t)(b * 256 + co) * 128 + h0) * 128 + w0 + l15;
#pragma unroll
      for (int nf = 0; nf < 4; ++nf) out[obase + nf * 16] = acc[mf][nf][r] + bias;
    }
  }
}

extern "C" void kernel_launch(void* const* d_in, const int* in_sizes, int n_in,
                              void* d_out, int out_size, void* d_ws, size_t ws_size,
                              hipStream_t stream) {
  const float* x      = (const float*)d_in[0];
  const float* wms    = (const float*)d_in[1];
  const float* conv_w = (const float*)d_in[2];
  const float* conv_b = (const float*)d_in[3];
  const float* e1w1   = (const float*)d_in[4];
  const float* e1b1   = (const float*)d_in[5];
  const float* e1w2   = (const float*)d_in[6];
  const float* e1b2   = (const float*)d_in[7];
  const float* e2w1   = (const float*)d_in[8];
  const float* e2b1   = (const float*)d_in[9];
  const float* e2w2   = (const float*)d_in[10];
  const float* e2b2   = (const float*)d_in[11];
  const float* A1     = (const float*)d_in[12];
  const float* A2     = (const float*)d_in[13];
  const float* loraB  = (const float*)d_in[14];
  float* out = (float*)d_out;

  uint8_t* ws = (uint8_t*)d_ws;
  __hip_bfloat16* zrow = (__hip_bfloat16*)(ws + OFF_ZROW);
  float* coff          = (float*)(ws + OFF_COFF);
  float* tmpS          = (float*)(ws + OFF_TMPS);
  __hip_bfloat16* Weff = (__hip_bfloat16*)(ws + OFF_WEFF);
  __hip_bfloat16* xT   = (__hip_bfloat16*)(ws + OFF_XT);

  // group size: how many samples' xT fit in ws
  int G = 16;
  while (G > 1 && (size_t)OFF_XT + (size_t)G * XT_PER_B > ws_size) G >>= 1;

  hipMemsetAsync(zrow, 0, 65536, stream);
  k_coff<<<32, 256, 0, stream>>>(wms, e1w1, e1b1, e1w2, e1b2, e2w1, e2b1, e2w2, e2b2, coff);
  k_tmps<<<256, 256, 0, stream>>>(coff, A1, A2, tmpS);
  k_weff<<<16 * 256, 256, 0, stream>>>(conv_w, loraB, tmpS, Weff);
  for (int g = 0; g < 16; g += G) {
    k_xt<<<G * 1024, 256, 0, stream>>>(x, xT, g);
    k_conv<<<G * 128, 256, 0, stream>>>(xT, Weff, zrow, conv_b, out, g);
  }
}

// Round 10
// 441.119 us; speedup vs baseline: 1.5984x; 1.5984x over previous
//
#include <hip/hip_runtime.h>
#include <hip/hip_bf16.h>
#include <stdint.h>

typedef __bf16 bf16x8 __attribute__((ext_vector_type(8)));
typedef float f32x4 __attribute__((ext_vector_type(4)));
typedef unsigned short ushort8v __attribute__((ext_vector_type(8)));

// Problem constants
#define NB    16
#define CIN   256
#define COUT  256
#define HH    128
#define WW    128

// ws layout (bytes)
#define OFF_ZROW  0u                    // 65536 zeroed page (one fake xT row)
#define OFF_COFF  (1u << 16)            // 2*16*256 f32 = 8 KB
#define OFF_TMPS  (1u << 17)            // 16*16*768 f32 = 768 KB
#define OFF_WEFF  (1u << 20)            // 16*9*256*256 bf16 = 18 MB
#define OFF_XT    (20u * 1024u * 1024u) // G * 8 MB bf16 channels-last x
#define XT_PER_B  (128u * 128u * 256u * 2u)

__device__ inline void gload16(const void* g, void* l) {
  __builtin_amdgcn_global_load_lds(
      (const __attribute__((address_space(1))) void*)g,
      (__attribute__((address_space(3))) void*)l, 16, 0, 0);
}

__device__ inline ushort f2bf(float f) {
  __hip_bfloat16 h = __float2bfloat16(f);
  union { __hip_bfloat16 b; ushort u; } cv;
  cv.b = h;
  return cv.u;
}

// ---------------- kernel 1: embed MLP -> coff[2][16][16][16] ----------------
__global__ void k_coff(const float* __restrict__ wms,
                       const float* __restrict__ w1a, const float* __restrict__ b1a,
                       const float* __restrict__ w2a, const float* __restrict__ b2a,
                       const float* __restrict__ w1b, const float* __restrict__ b1b,
                       const float* __restrict__ w2b, const float* __restrict__ b2b,
                       float* __restrict__ coff) {
  int br = blockIdx.x >> 4, b = blockIdx.x & 15;
  const float* w1 = br ? w1b : w1a;
  const float* b1 = br ? b1b : b1a;
  const float* w2 = br ? w2b : w2a;
  const float* b2 = br ? b2b : b2a;
  const float* v = wms + (br * 16 + b) * 32;
  __shared__ float h[128];
  int t = threadIdx.x;
  if (t < 128) {
    float a = b1[t];
#pragma unroll
    for (int i = 0; i < 32; ++i) a += w1[t * 32 + i] * v[i];
    h[t] = a >= 0.f ? a : 0.2f * a;
  }
  __syncthreads();
  float a = b2[t];
  for (int j = 0; j < 128; ++j) a += w2[t * 128 + j] * h[j];
  coff[(br * 16 + b) * 256 + t] = a;
}

// ------------- kernel 2a: tmpS[b][r][c] = coff1@A1 + coff2@A2 ---------------
__global__ void k_tmps(const float* __restrict__ coff,
                       const float* __restrict__ A1, const float* __restrict__ A2,
                       float* __restrict__ tmpS) {
  int b = blockIdx.x >> 4, r = blockIdx.x & 15;
  __shared__ float c1[16], c2[16];
  int t = threadIdx.x;
  if (t < 16) {
    c1[t] = coff[b * 256 + r * 16 + t];
    c2[t] = coff[(16 + b) * 256 + r * 16 + t];
  }
  __syncthreads();
  for (int c = t; c < 768; c += 256) {
    float s = 0.f;
#pragma unroll
    for (int q = 0; q < 16; ++q) s += c1[q] * A1[q * 768 + c] + c2[q] * A2[q * 768 + c];
    tmpS[(b * 16 + r) * 768 + c] = s;
  }
}

// ------- kernel 2b: Weff[b][tt][co][ci] = conv_w + loraB @ tmpS (bf16) -------
__global__ __launch_bounds__(256) void k_weff(const float* __restrict__ conv_w,
                                              const float* __restrict__ loraB,
                                              const float* __restrict__ tmpS,
                                              __hip_bfloat16* __restrict__ Weff) {
  int bid = blockIdx.x;
  int co = bid & 255, b = bid >> 8;
  int t = threadIdx.x;
  __shared__ float Bs[3][16];
  __shared__ ushort obuf[2304];
  if (t < 48) Bs[t >> 4][t & 15] = loraB[(co * 3 + (t >> 4)) * 16 + (t & 15)];
  __syncthreads();
  const float* T = tmpS + (size_t)b * 16 * 768;
  const float* W = conv_w + (size_t)co * 2304;
#pragma unroll
  for (int k = 0; k < 3; ++k) {
#pragma unroll
    for (int cc = 0; cc < 3; ++cc) {
      int c = cc * 256 + t;
      float s = W[k * 768 + c];
#pragma unroll
      for (int r = 0; r < 16; ++r) s += Bs[k][r] * T[r * 768 + c];
      int f = k * 768 + c;  // local flat over (ci,kh,kw) for this co
      int ci = f / 9, tt = f - ci * 9;
      obuf[tt * 256 + ci] = f2bf(s);
    }
  }
  __syncthreads();
#pragma unroll
  for (int tt = 0; tt < 9; ++tt)
    ((ushort*)Weff)[((size_t)(b * 9 + tt) * 256 + co) * 256 + t] = obuf[tt * 256 + t];
}

// -------- kernel 3: x (f32, NCHW) -> xT (bf16, N H W C channels-last) --------
__global__ __launch_bounds__(256) void k_xt(const float* __restrict__ x,
                                            __hip_bfloat16* __restrict__ xT, int b0) {
  __shared__ ushort t[32][132];
  int bid = blockIdx.x;
  int cb = bid & 7, h = (bid >> 3) & 127, bp = bid >> 10;
  int b = b0 + bp;
  int tid = threadIdx.x;
  int ci2 = tid >> 5, w4 = (tid & 31) * 4;
  const float* srcb = x + ((size_t)(b * 256 + cb * 32) * 128 + h) * 128;
#pragma unroll
  for (int k = 0; k < 4; ++k) {
    int c = ci2 + k * 8;
    float4 v = *(const float4*)(srcb + (size_t)c * 16384 + w4);
    ushort4 u;
    u.x = f2bf(v.x);
    u.y = f2bf(v.y);
    u.z = f2bf(v.z);
    u.w = f2bf(v.w);
    *(ushort4*)&t[c][w4] = u;
  }
  __syncthreads();
  int w = tid >> 1, hf = tid & 1;
  ushort8v o0, o1;
#pragma unroll
  for (int j = 0; j < 8; ++j) {
    o0[j] = t[hf * 16 + j][w];
    o1[j] = t[hf * 16 + 8 + j][w];
  }
  ushort* dst = (ushort*)xT + (size_t)bp * 128 * 128 * 256 +
                ((size_t)h * 128 + w) * 256 + cb * 32 + hf * 16;
  *(ushort8v*)dst = o0;
  *(ushort8v*)(dst + 8) = o1;
}

// ------------------- kernel 4: per-sample implicit-GEMM conv ------------------
// 3 blocks/CU (12 waves, 3/SIMD): block tile 128co x 128w x 1 row, 4 waves of
// 64co x 64px (acc 64 AGPR). LDS 49.5 KB/block. Schedule + frag patterns +
// granule swizzle g' = g ^ ((row>>1)&3) byte-identical logic to R7 (0
// conflicts proven). No setprio (m190: hurts lockstep GEMM), no desync (R8
// proven neutral). The 3rd wave per SIMD is the latency-hiding partner the
// previous rounds lacked.
__global__ __launch_bounds__(256, 3) void k_conv(
    const __hip_bfloat16* __restrict__ xT,
    const __hip_bfloat16* __restrict__ Weff,
    const __hip_bfloat16* __restrict__ zrow,
    const float* __restrict__ cbias,
    float* __restrict__ out, int b0) {
  // xs[ri][wi][ci] : ri 0..2 -> x row h0-1+ri ; wi 0..129 -> w = wi-1 ; 32 ci
  __shared__ __align__(16) __hip_bfloat16 xs[3 * 130 * 32];   // 24,960 B
  // wbuf[kw][co][ci] : 3 x 128 x 32 (this block's co-half, one kh at a time)
  __shared__ __align__(16) __hip_bfloat16 wbuf[3 * 128 * 32]; // 24,576 B

  // XCD-aware swizzle (nwg = G*256, always % 8 == 0)
  int nwg = gridDim.x;
  int bid0 = blockIdx.x;
  int bid = (bid0 & 7) * (nwg >> 3) + (bid0 >> 3);

  int h0 = bid & 127, coh = (bid >> 7) & 1, bp = bid >> 8;
  int b = b0 + bp;

  int tid = threadIdx.x;
  int wid = tid >> 6, lane = tid & 63;
  int l15 = lane & 15, lh = lane >> 4;
  int wm = wid >> 1;                // co quarter within half (0/1) -> 64 co
  int w0 = (wid & 1) * 64;          // w half
  int lrow = lane >> 2;
  int sgx = (lane & 3) ^ (((1 + lrow) >> 1) & 3);  // x-stage source granule
  int sgw = (lane & 3) ^ ((lrow >> 1) & 3);        // w-stage source granule
  int asw = (l15 >> 1) & 3;                        // A-frag read swizzle

  // zero the w-pad columns (wi = 0 and wi = 129); never overwritten after
  if (tid < 192) {
    int ri = tid >> 6, which = (tid >> 5) & 1, ci = tid & 31;
    ((ushort*)xs)[ri * 4160 + (which ? 129 : 0) * 32 + ci] = 0;
  }

  // ---- precomputed offsets (elements) ----
  int a_base = (wm * 64 + l15) * 32 + (lh ^ asw) * 8;   // + kw*4096 + mf*512
  int b_base0 = (w0 + l15 + 0) * 32 + ((lh ^ (((l15 + 0) >> 1) & 3)) * 8);
  int b_base1 = (w0 + l15 + 1) * 32 + ((lh ^ (((l15 + 1) >> 1) & 3)) * 8);
  int b_base2 = (w0 + l15 + 2) * 32 + ((lh ^ (((l15 + 2) >> 1) & 3)) * 8);
  int xoff = lrow * 256 + sgx * 8;               // + wblk*4096 + c0
  int woff = (coh * 128 + lrow) * 256 + sgw * 8; // + kw*65536 + cblk*4096 + c0

  const __hip_bfloat16* xTb = xT + (size_t)bp * 128 * 128 * 256;
  const __hip_bfloat16* r0 = (h0 > 0)   ? xTb + (size_t)(h0 - 1) * 32768 : zrow;
  const __hip_bfloat16* r1 = xTb + (size_t)h0 * 32768;
  const __hip_bfloat16* r2 = (h0 < 127) ? xTb + (size_t)(h0 + 1) * 32768 : zrow;

  f32x4 acc[4][4];
#pragma unroll
  for (int mf = 0; mf < 4; ++mf)
#pragma unroll
    for (int nf = 0; nf < 4; ++nf) acc[mf][nf] = (f32x4){0.f, 0.f, 0.f, 0.f};

  for (int cb8 = 0; cb8 < 8; ++cb8) {
    int c0 = cb8 * 32;
    __syncthreads();  // previous phase done reading xs/wbuf

    // stage x: 24 x (1KB gload16); slot = k*4+wid -> ri = k>>1 compile-time
#pragma unroll
    for (int k = 0; k < 6; ++k) {
      const int ri = k >> 1;
      int wblk = (k & 1) * 4 + wid;
      const __hip_bfloat16* rp = (ri == 0) ? r0 : ((ri == 1) ? r1 : r2);
      gload16((const void*)(rp + wblk * 4096 + c0 + xoff),
              (void*)(xs + ri * 4160 + (1 + wblk * 16) * 32));
    }

    // stage W for kh, then compute; 3 kh phases
#pragma unroll 1
    for (int kh = 0; kh < 3; ++kh) {
      if (kh) __syncthreads();  // compute(kh-1) done reading wbuf
      const __hip_bfloat16* wtap =
          Weff + ((size_t)(b * 9 + kh * 3) << 16) + c0 + woff;
      // slot = k*4+wid -> kw = k>>1 compile-time, cblk = (k&1)*4+wid (16 co)
#pragma unroll
      for (int k = 0; k < 6; ++k) {
        const int kw = k >> 1;
        int cblk = (k & 1) * 4 + wid;
        gload16((const void*)(wtap + kw * 65536 + cblk * 4096),
                (void*)(wbuf + kw * 4096 + cblk * 512));
      }
      __syncthreads();  // staging complete (syncthreads drains vmcnt)

#pragma unroll
      for (int kw = 0; kw < 3; ++kw) {
        int bb = (kw == 0) ? b_base0 : ((kw == 1) ? b_base1 : b_base2);
        bf16x8 af[4], bfr[4];
#pragma unroll
        for (int mf = 0; mf < 4; ++mf)
          af[mf] = *(const bf16x8*)&wbuf[kw * 4096 + a_base + mf * 512];
#pragma unroll
        for (int nf = 0; nf < 4; ++nf)
          bfr[nf] = *(const bf16x8*)&xs[kh * 4160 + bb + nf * 512];
#pragma unroll
        for (int mf = 0; mf < 4; ++mf)
#pragma unroll
          for (int nf = 0; nf < 4; ++nf)
            acc[mf][nf] = __builtin_amdgcn_mfma_f32_16x16x32_bf16(af[mf], bfr[nf],
                                                                  acc[mf][nf], 0, 0, 0);
      }
    }
  }

  // epilogue: D[m][n]: m(co) = (lane>>4)*4 + r, n(px) = lane&15
#pragma unroll
  for (int mf = 0; mf < 4; ++mf) {
    int cobase = coh * 128 + wm * 64 + mf * 16 + lh * 4;
#pragma unroll
    for (int r = 0; r < 4; ++r) {
      int co = cobase + r;
      float bias = cbias[co];
      size_t obase = ((size_t)(b * 256 + co) * 128 + h0) * 128 + w0 + l15;
#pragma unroll
      for (int nf = 0; nf < 4; ++nf) out[obase + nf * 16] = acc[mf][nf][r] + bias;
    }
  }
}

extern "C" void kernel_launch(void* const* d_in, const int* in_sizes, int n_in,
                              void* d_out, int out_size, void* d_ws, size_t ws_size,
                              hipStream_t stream) {
  const float* x      = (const float*)d_in[0];
  const float* wms    = (const float*)d_in[1];
  const float* conv_w = (const float*)d_in[2];
  const float* conv_b = (const float*)d_in[3];
  const float* e1w1   = (const float*)d_in[4];
  const float* e1b1   = (const float*)d_in[5];
  const float* e1w2   = (const float*)d_in[6];
  const float* e1b2   = (const float*)d_in[7];
  const float* e2w1   = (const float*)d_in[8];
  const float* e2b1   = (const float*)d_in[9];
  const float* e2w2   = (const float*)d_in[10];
  const float* e2b2   = (const float*)d_in[11];
  const float* A1     = (const float*)d_in[12];
  const float* A2     = (const float*)d_in[13];
  const float* loraB  = (const float*)d_in[14];
  float* out = (float*)d_out;

  uint8_t* ws = (uint8_t*)d_ws;
  __hip_bfloat16* zrow = (__hip_bfloat16*)(ws + OFF_ZROW);
  float* coff          = (float*)(ws + OFF_COFF);
  float* tmpS          = (float*)(ws + OFF_TMPS);
  __hip_bfloat16* Weff = (__hip_bfloat16*)(ws + OFF_WEFF);
  __hip_bfloat16* xT   = (__hip_bfloat16*)(ws + OFF_XT);

  // group size: how many samples' xT fit in ws
  int G = 16;
  while (G > 1 && (size_t)OFF_XT + (size_t)G * XT_PER_B > ws_size) G >>= 1;

  hipMemsetAsync(zrow, 0, 65536, stream);
  k_coff<<<32, 256, 0, stream>>>(wms, e1w1, e1b1, e1w2, e1b2, e2w1, e2b1, e2w2, e2b2, coff);
  k_tmps<<<256, 256, 0, stream>>>(coff, A1, A2, tmpS);
  k_weff<<<16 * 256, 256, 0, stream>>>(conv_w, loraB, tmpS, Weff);
  for (int g = 0; g < 16; g += G) {
    k_xt<<<G * 1024, 256, 0, stream>>>(x, xT, g);
    k_conv<<<G * 256, 256, 0, stream>>>(xT, Weff, zrow, conv_b, out, g);
  }
}